// Round 18
// baseline (326.755 us; speedup 1.0000x reference)
//
#include <hip/hip_runtime.h>
#include <hip/hip_bf16.h>

#define Bn 256
#define Tn 200
#define En 100
#define Hn 128
#define Kn 13
#define G4 512          // 4H
#define BT 51200        // B*T

typedef __attribute__((ext_vector_type(8))) __bf16 bf8_t;
typedef __attribute__((ext_vector_type(4))) float f4_t;

__device__ __forceinline__ unsigned short f2bf(float f) {
  unsigned int u = __float_as_uint(f);
  u = (u + 0x7FFFu + ((u >> 16) & 1u)) >> 16;
  return (unsigned short)u;
}
__device__ __forceinline__ float bf2f(unsigned short s) {
  return __uint_as_float(((unsigned int)s) << 16);
}
__device__ __forceinline__ float sigm(float x) { return 1.f / (1.f + __expf(-x)); }

// LDS-only barrier: drains lgkmcnt but lets VMEM stay in flight across it.
__device__ __forceinline__ void bar_lgkm() {
  asm volatile("s_waitcnt lgkmcnt(0)" ::: "memory");
  __builtin_amdgcn_s_barrier();
  __builtin_amdgcn_sched_barrier(0);
}

// Gate permutation: permuted col n holds original col g*128 + j with
// g=(n>>4)&3, j=(n>>6)*16+(n&15).
__device__ __forceinline__ int gperm(int n) {
  return ((n >> 4) & 3) * 128 + ((n >> 6) << 4) + (n & 15);
}

#define MFMA(a, b, c) __builtin_amdgcn_mfma_f32_16x16x32_bf16(a, b, c, 0, 0, 0)

// ---------- prep: wt/ut transpose-permute (blocks 0..1023) + lens (1024..1087) ----------
__global__ __launch_bounds__(256) void k_prep(const int* __restrict__ text,
                                              const float* __restrict__ Wf,
                                              const float* __restrict__ Wb,
                                              const float* __restrict__ Uf,
                                              const float* __restrict__ Ub,
                                              unsigned short* __restrict__ wt,
                                              unsigned short* __restrict__ ut,
                                              int* __restrict__ lens_i,
                                              float* __restrict__ out_lens) {
  int bx = blockIdx.x;
  if (bx < 1024) {
    int idx = bx * 256 + threadIdx.x;   // 0..262143
    int half = idx >> 17;               // 0:W  1:U
    int rem = idx & 131071;
    int dir = rem >> 16;
    int nk = rem & 65535;
    int n = nk >> 7, k = nk & 127;
    int mc = gperm(n);
    if (half == 0) {
      const float* W = dir ? Wb : Wf;
      wt[rem] = f2bf((k < En) ? W[k * G4 + mc] : 0.f);
    } else {
      const float* U = dir ? Ub : Uf;
      ut[rem] = f2bf(U[k * G4 + mc]);
    }
  } else {
    int wi = threadIdx.x >> 6, lane = threadIdx.x & 63;
    int b = (bx - 1024) * 4 + wi;
    int cnt = 0;
    for (int t = lane; t < Tn; t += 64) cnt += (text[b * Tn + t] != 0);
    for (int off = 32; off; off >>= 1) cnt += __shfl_down(cnt, off);
    if (lane == 0) { lens_i[b] = cnt; out_lens[b] = (float)cnt; }
  }
}

// ---------- fused recurrent scan (R18): 4-wave consolidation ----------
// R17 post-mortem: per-step 2011 cyc; LDS pipe (per-CU, shared by 4 SIMDs) was
// the limit: 8 waves x 8 ds_read_b128 x ~12cyc = 768 cyc/step of REDUNDANT
// A-operand reads (every wave reads the same 4KB h + 4KB x tile). R18: 4 waves
// x 128 cols (8 nt each) -- per-thread af/ax reads stay 4+4 (regs reused
// across nt) so block LDS reads HALVE; 64 MFMA/wave spread on 4 SIMDs at
// 1 wave each. U+W = 64 frags = 256 AGPR; ~170 VGPR; waves_per_eu(1,1)
// gives the 512-reg budget. Bias folded into kk=0 MFMA C-operand.
#define NT8K4(M) M(0,0) M(0,1) M(0,2) M(0,3) M(1,0) M(1,1) M(1,2) M(1,3) \
                 M(2,0) M(2,1) M(2,2) M(2,3) M(3,0) M(3,1) M(3,2) M(3,3) \
                 M(4,0) M(4,1) M(4,2) M(4,3) M(5,0) M(5,1) M(5,2) M(5,3) \
                 M(6,0) M(6,1) M(6,2) M(6,3) M(7,0) M(7,1) M(7,2) M(7,3)

#define MFUK(P, kk) \
    P##0 = MFMA(af##kk, ub_0_##kk, P##0); \
    P##1 = MFMA(af##kk, ub_1_##kk, P##1); \
    P##2 = MFMA(af##kk, ub_2_##kk, P##2); \
    P##3 = MFMA(af##kk, ub_3_##kk, P##3); \
    P##4 = MFMA(af##kk, ub_4_##kk, P##4); \
    P##5 = MFMA(af##kk, ub_5_##kk, P##5); \
    P##6 = MFMA(af##kk, ub_6_##kk, P##6); \
    P##7 = MFMA(af##kk, ub_7_##kk, P##7);

#define MFW0(Q) \
    Q##0 = MFMA(ax0, wb_0_0, bv0); \
    Q##1 = MFMA(ax0, wb_1_0, bv1); \
    Q##2 = MFMA(ax0, wb_2_0, bv2); \
    Q##3 = MFMA(ax0, wb_3_0, bv3); \
    Q##4 = MFMA(ax0, wb_4_0, bv4); \
    Q##5 = MFMA(ax0, wb_5_0, bv5); \
    Q##6 = MFMA(ax0, wb_6_0, bv6); \
    Q##7 = MFMA(ax0, wb_7_0, bv7);

#define MFWK(Q, kk) \
    Q##0 = MFMA(ax##kk, wb_0_##kk, Q##0); \
    Q##1 = MFMA(ax##kk, wb_1_##kk, Q##1); \
    Q##2 = MFMA(ax##kk, wb_2_##kk, Q##2); \
    Q##3 = MFMA(ax##kk, wb_3_##kk, Q##3); \
    Q##4 = MFMA(ax##kk, wb_4_##kk, Q##4); \
    Q##5 = MFMA(ax##kk, wb_5_##kk, Q##5); \
    Q##6 = MFMA(ax##kk, wb_6_##kk, Q##6); \
    Q##7 = MFMA(ax##kk, wb_7_##kk, Q##7);

__global__ __attribute__((amdgpu_flat_work_group_size(256, 256),
                          amdgpu_waves_per_eu(1, 1)))
void k_scan(const int* __restrict__ text,
            const float* __restrict__ emb,
            const unsigned short* __restrict__ wt,
            const unsigned short* __restrict__ ut,
            const float* __restrict__ biasf,
            const float* __restrict__ biasb,
            unsigned short* __restrict__ hf,
            unsigned short* __restrict__ hb) {
  int blk = blockIdx.x;              // 0..127
  int dir = blk >> 6;
  int bg = blk & 63;
  int b0 = bg * 4;
  int tid = threadIdx.x;             // 0..255 (4 waves)
  int w = tid >> 6, l = tid & 63;
  int lr = l & 15, lg = l >> 4;
  int j0 = w * 32 + lr;              // this lane's unit 0 (nt 0..3 = its gates)
  // unit 1 = j0 + 16 (nt 4..7)
  const unsigned short* ut_d = ut + (size_t)dir * (G4 * 128);
  const unsigned short* wt_d = wt + (size_t)dir * (G4 * 128);
  const float* bias = dir ? biasb : biasf;
  unsigned short* hout = dir ? hb : hf;
  int t0 = dir ? (Tn - 1) : 0;
  int dt = dir ? -1 : 1;

  // U and W B-frags pinned into AGPRs (64 frags = 256 AGPR); col(nt) = w*128+nt*16+lr
#define LOADUB(nt, kk) \
  bf8_t ub_##nt##_##kk = *(const bf8_t*)(ut_d + (size_t)(w * 128 + (nt) * 16 + lr) * 128 + (kk) * 32 + lg * 8); \
  asm volatile("" : "+a"(ub_##nt##_##kk));
  NT8K4(LOADUB)
#undef LOADUB
#define LOADWB(nt, kk) \
  bf8_t wb_##nt##_##kk = *(const bf8_t*)(wt_d + (size_t)(w * 128 + (nt) * 16 + lr) * 128 + (kk) * 32 + lg * 8); \
  asm volatile("" : "+a"(wb_##nt##_##kk));
  NT8K4(LOADWB)
#undef LOADWB

  // LDS: h dbuf [0,8K) ; x dbuf [8K,16K) ; tokens [16K,16K+3200)
  __shared__ __align__(16) char lds_all[16384 + Tn * 4 * 4];
  char* lbase = lds_all;
  int* tl = (int*)(lds_all + 16384);
  for (int i = tid; i < 4096; i += 256) ((unsigned int*)lds_all)[i] = 0;
  #pragma unroll
  for (int r = 0; r < 4; r++)
    if (tid < Tn) tl[r * Tn + tid] = text[(size_t)(b0 + r) * Tn + tid];

  // bias C-init vectors (constant; consumed as kk=0 MFMA C-operand)
  f4_t bv0, bv1, bv2, bv3, bv4, bv5, bv6, bv7;
#define LBIAS(nt) { float b_ = bias[gperm(w * 128 + (nt) * 16 + lr)]; \
  bv##nt[0] = b_; bv##nt[1] = b_; bv##nt[2] = b_; bv##nt[3] = b_; }
  LBIAS(0) LBIAS(1) LBIAS(2) LBIAS(3) LBIAS(4) LBIAS(5) LBIAS(6) LBIAS(7)
#undef LBIAS

  // x gather duty: 2 (row,col) pairs per thread: rows xr0 and xr0+2, col xc
  int xr0 = tid >> 7;                // 0..1
  int xc = tid & 127;
  bool xon = (xc < En);
  float v00 = 0.f, v01 = 0.f;        // x[t0] rows xr0, xr0+2
  float v10 = 0.f, v11 = 0.f;        // x[t0+dt]
  float vA0 = 0.f, vA1 = 0.f;        // x[t0+2dt]
  float vB0 = 0.f, vB1 = 0.f;        // x[t0+3dt]
  {
    const int* tr0 = text + (size_t)(b0 + xr0) * Tn;
    const int* tr1 = text + (size_t)(b0 + xr0 + 2) * Tn;
    if (xon) {
      v00 = emb[(size_t)tr0[t0] * En + xc];
      v01 = emb[(size_t)tr1[t0] * En + xc];
      v10 = emb[(size_t)tr0[t0 + dt] * En + xc];
      v11 = emb[(size_t)tr1[t0 + dt] * En + xc];
      vA0 = emb[(size_t)tr0[t0 + 2 * dt] * En + xc];
      vA1 = emb[(size_t)tr1[t0 + 2 * dt] * En + xc];
      vB0 = emb[(size_t)tr0[t0 + 3 * dt] * En + xc];
      vB1 = emb[(size_t)tr1[t0 + 3 * dt] * En + xc];
    }
  }

  // LDS addresses; h: read buf0 / write buf1; x: read bufB / write bufA
  int rb0 = (lr * 256 +   0 + lg * 16) ^ ((lr & 7) << 4);
  int rb1 = (lr * 256 +  64 + lg * 16) ^ ((lr & 7) << 4);
  int rb2 = (lr * 256 + 128 + lg * 16) ^ ((lr & 7) << 4);
  int rb3 = (lr * 256 + 192 + lg * 16) ^ ((lr & 7) << 4);
  int xb0 = 12288 + rb0, xb1 = 12288 + rb1, xb2 = 12288 + rb2, xb3 = 12288 + rb3;
  int hrow = lg * 4;
  int hsw = ((hrow & 7) << 4);
  int wbh0 = ((hrow * 256 + j0 * 2) ^ hsw) + 4096;
  int wbh1 = ((hrow * 256 + (j0 + 16) * 2) ^ hsw) + 4096;
  int xrow0b = (xr0 * 4) * 256;            // rows 0 / 4
  int xrow1b = ((xr0 + 2) * 4) * 256;      // rows 8 / 12
  int wbx0 = 8192 + ((xrow0b + xc * 2) ^ (((xr0 * 4) & 7) << 4));
  int wbx1 = 8192 + ((xrow1b + xc * 2) ^ ((((xr0 + 2) * 4) & 7) << 4));

  unsigned short* hp = hout + ((size_t)t0 * Bn + b0 + lg) * 128 + j0;
  const long long hstep = (long long)dt * Bn * 128;

  // publish x[t0] -> bufA, x[t0+dt] -> bufB
  *(unsigned short*)(lbase + wbx0) = f2bf(v00);
  *(unsigned short*)(lbase + wbx1) = f2bf(v01);
  *(unsigned short*)(lbase + (wbx0 ^ 4096)) = f2bf(v10);
  *(unsigned short*)(lbase + (wbx1 ^ 4096)) = f2bf(v11);
  bar_lgkm();                             // zeros + tokens + x publishes visible

  // prologue: P = bias + x[t0]@W (reads bufA frags)
  f4_t pA0, pA1, pA2, pA3, pA4, pA5, pA6, pA7;
  f4_t pB0, pB1, pB2, pB3, pB4, pB5, pB6, pB7;
  {
    bf8_t ax0 = *(const bf8_t*)(lbase + 8192 + rb0);
    bf8_t ax1 = *(const bf8_t*)(lbase + 8192 + rb1);
    bf8_t ax2 = *(const bf8_t*)(lbase + 8192 + rb2);
    bf8_t ax3 = *(const bf8_t*)(lbase + 8192 + rb3);
    MFW0(pA) MFWK(pA, 1) MFWK(pA, 2) MFWK(pA, 3)
  }
  float c0 = 0.f, c1 = 0.f;
  int t = t0;

  // STEP(P, Q): gates from P (extended by h@U); Q = bias + x[t+1]@W for next step
#define STEPF(P, Q) { \
    bf8_t af0 = *(const bf8_t*)(lbase + rb0); \
    bf8_t af1 = *(const bf8_t*)(lbase + rb1); \
    bf8_t af2 = *(const bf8_t*)(lbase + rb2); \
    bf8_t af3 = *(const bf8_t*)(lbase + rb3); \
    bf8_t ax0 = *(const bf8_t*)(lbase + xb0); \
    bf8_t ax1 = *(const bf8_t*)(lbase + xb1); \
    bf8_t ax2 = *(const bf8_t*)(lbase + xb2); \
    bf8_t ax3 = *(const bf8_t*)(lbase + xb3); \
    /* publish x[t+2]; rotate pipeline; load x[t+3] */ \
    *(unsigned short*)(lbase + wbx0) = f2bf(vA0); \
    *(unsigned short*)(lbase + wbx1) = f2bf(vA1); \
    vA0 = vB0; vA1 = vB1; \
    { int tc = t + 3 * dt; tc = tc < 0 ? 0 : (tc > Tn - 1 ? Tn - 1 : tc); \
      int tk0 = tl[xr0 * Tn + tc]; \
      int tk1 = tl[(xr0 + 2) * Tn + tc]; \
      vB0 = xon ? emb[(size_t)tk0 * En + xc] : 0.f; \
      vB1 = xon ? emb[(size_t)tk1 * En + xc] : 0.f; } \
    /* h@U extends P in place (P already = bias + x_t@W) */ \
    MFUK(P, 0) MFUK(P, 1) MFUK(P, 2) MFUK(P, 3) \
    /* x[t+1]@W into Q (off critical path) */ \
    MFW0(Q) MFWK(Q, 1) MFWK(Q, 2) MFWK(Q, 3) \
    /* gates: unit j0 from P0..3, unit j0+16 from P4..7 */ \
    float ig0 = sigm(P##0[0]); \
    float fg0 = sigm(P##1[0]); \
    float gg0 = fmaxf(P##2[0], 0.f); \
    c0 = fmaf(fg0, c0, ig0 * gg0); \
    unsigned short h0s = f2bf(sigm(P##3[0]) * fmaxf(c0, 0.f)); \
    float ig1 = sigm(P##4[0]); \
    float fg1 = sigm(P##5[0]); \
    float gg1 = fmaxf(P##6[0], 0.f); \
    c1 = fmaf(fg1, c1, ig1 * gg1); \
    unsigned short h1s = f2bf(sigm(P##7[0]) * fmaxf(c1, 0.f)); \
    *(unsigned short*)(lbase + wbh0) = h0s; \
    *(unsigned short*)(lbase + wbh1) = h1s; \
    bar_lgkm(); \
    hp[0] = h0s; hp[16] = h1s; \
    rb0 ^= 4096; rb1 ^= 4096; rb2 ^= 4096; rb3 ^= 4096; \
    xb0 ^= 4096; xb1 ^= 4096; xb2 ^= 4096; xb3 ^= 4096; \
    wbh0 ^= 4096; wbh1 ^= 4096; wbx0 ^= 4096; wbx1 ^= 4096; \
    hp += hstep; \
    t += dt; }

  for (int tt = 0; tt < Tn; tt += 2) {
    STEPF(pA, pB)
    STEPF(pB, pA)
  }
#undef STEPF
}

// ---------- logits = softmax([hf|hb] @ Wd + bd); h rows are (t*Bn+b) ----------
__global__ __launch_bounds__(128) void k_logits(const unsigned short* __restrict__ hf,
                                                const unsigned short* __restrict__ hb,
                                                const float* __restrict__ Wd,
                                                const float* __restrict__ bd,
                                                float* __restrict__ out) {
  __shared__ unsigned short hs[128 * 256];   // 64KB, XOR-swizzled rows of 512B
  int tid = threadIdx.x;
  size_t row0 = (size_t)blockIdx.x * 128;
  #pragma unroll
  for (int it = 0; it < 16; it++) {
    int idx = it * 128 + tid;
    int r = idx >> 4, c = idx & 15;
    bf8_t vf = *(const bf8_t*)(hf + (row0 + r) * 128 + c * 8);
    bf8_t vb = *(const bf8_t*)(hb + (row0 + r) * 128 + c * 8);
    int byte = (r * 512 + c * 16) ^ ((r & 7) << 4);
    *(bf8_t*)((char*)hs + byte) = vf;
    int byte2 = (r * 512 + 256 + c * 16) ^ ((r & 7) << 4);
    *(bf8_t*)((char*)hs + byte2) = vb;
  }
  __syncthreads();
  float acc[Kn];
  #pragma unroll
  for (int jj = 0; jj < Kn; jj++) acc[jj] = bd[jj];
  int r = tid;
  #pragma unroll 4
  for (int c = 0; c < 32; c++) {
    int byte = (r * 512 + c * 16) ^ ((r & 7) << 4);
    bf8_t v = *(const bf8_t*)((const char*)hs + byte);
    #pragma unroll
    for (int e = 0; e < 8; e++) {
      float h = (float)v[e];
      int k = c * 8 + e;
      #pragma unroll
      for (int jj = 0; jj < Kn; jj++)
        acc[jj] = fmaf(h, Wd[k * Kn + jj], acc[jj]);   // uniform -> scalar loads
    }
  }
  float m = acc[0];
  #pragma unroll
  for (int jj = 1; jj < Kn; jj++) m = fmaxf(m, acc[jj]);
  float s = 0.f;
  #pragma unroll
  for (int jj = 0; jj < Kn; jj++) { acc[jj] = __expf(acc[jj] - m); s += acc[jj]; }
  float inv = 1.f / s;
  int rg = (int)row0 + tid;          // h row index = t*Bn + b
  int b = rg & 255, t = rg >> 8;
  float* op = out + ((size_t)b * Tn + t) * Kn;
  #pragma unroll
  for (int jj = 0; jj < Kn; jj++) op[jj] = acc[jj] * inv;
}

// ---------- CRF log-likelihood: one wave per batch row ----------
__global__ __launch_bounds__(64) void k_crf(const float* __restrict__ logits,
                                            const int* __restrict__ labels,
                                            const int* __restrict__ lens_i,
                                            const float* __restrict__ trans,
                                            float* __restrict__ out_ll) {
  int b = blockIdx.x, lane = threadIdx.x;
  int len = lens_i[b];
  const float* lg = logits + (size_t)b * Tn * Kn;
  const int* lab = labels + (size_t)b * Tn;
  float sc = 0.f;
  for (int t = lane; t < Tn; t += 64) {
    if (t < len) {
      sc += lg[t * Kn + lab[t]];
      if (t >= 1) sc += trans[lab[t - 1] * Kn + lab[t]];
    }
  }
  for (int off = 32; off; off >>= 1) sc += __shfl_down(sc, off);
  bool act = lane < Kn;
  int jl = act ? lane : 0;
  float etr[Kn];
  #pragma unroll
  for (int i = 0; i < Kn; i++) etr[i] = __expf(trans[i * Kn + jl]);
  float a = act ? lg[jl] : -INFINITY;
  float lgv = (len > 1) ? lg[Kn + jl] : 0.f;
  for (int t = 1; t < len; t++) {
    float lgn = (t + 1 < len) ? lg[(t + 1) * Kn + jl] : 0.f;
    float m = a;
    for (int off = 8; off; off >>= 1) m = fmaxf(m, __shfl_xor(m, off, 16));
    float ea = __expf(a - m);
    float s = 0.f;
    #pragma unroll
    for (int i = 0; i < Kn; i++) s = fmaf(__shfl(ea, i), etr[i], s);
    float anew = m + __logf(s) + lgv;
    if (act) a = anew;
    lgv = lgn;
  }
  float m2 = a;
  for (int off = 8; off; off >>= 1) m2 = fmaxf(m2, __shfl_xor(m2, off, 16));
  float ea2 = act ? __expf(a - m2) : 0.f;
  float ssum = ea2;
  for (int off = 8; off; off >>= 1) ssum += __shfl_xor(ssum, off, 16);
  float logZ = m2 + __logf(ssum);
  if (lane == 0) out_ll[b] = sc - logZ;
}

extern "C" void kernel_launch(void* const* d_in, const int* in_sizes, int n_in,
                              void* d_out, int out_size, void* d_ws, size_t ws_size,
                              hipStream_t stream) {
  const int* text = (const int*)d_in[0];
  const int* labels = (const int*)d_in[1];
  const float* emb = (const float*)d_in[2];
  const float* Wf = (const float*)d_in[3];
  const float* Uf = (const float*)d_in[4];
  const float* bf_ = (const float*)d_in[5];
  const float* Wb = (const float*)d_in[6];
  const float* Ub = (const float*)d_in[7];
  const float* bb_ = (const float*)d_in[8];
  const float* Wd = (const float*)d_in[9];
  const float* bd = (const float*)d_in[10];
  const float* trans = (const float*)d_in[11];
  (void)in_sizes; (void)n_in; (void)out_size; (void)ws_size;

  float* out = (float*)d_out;
  float* out_logits = out;                       // [BT*K]
  float* out_lens = out + (size_t)BT * Kn;       // [B]
  float* out_ll = out_lens + Bn;                 // [B]

  char* ws = (char*)d_ws;
  size_t o = 0;
  int* lens_i = (int*)(ws + o);                o += 1024;
  unsigned short* wt = (unsigned short*)(ws + o);  o += (size_t)2 * G4 * 128 * 2;
  unsigned short* ut = (unsigned short*)(ws + o);  o += (size_t)2 * G4 * 128 * 2;
  unsigned short* hfb = (unsigned short*)(ws + o); o += (size_t)BT * Hn * 2;       // [t][b][128]
  unsigned short* hbb = (unsigned short*)(ws + o); o += (size_t)BT * Hn * 2;

  hipLaunchKernelGGL(k_prep, dim3(1088), dim3(256), 0, stream,
                     text, Wf, Wb, Uf, Ub, wt, ut, lens_i, out_lens);
  hipLaunchKernelGGL(k_scan, dim3(128), dim3(256), 0, stream,
                     text, emb, wt, ut, bf_, bb_, hfb, hbb);
  hipLaunchKernelGGL(k_logits, dim3(400), dim3(128), 0, stream, hfb, hbb, Wd, bd, out_logits);
  hipLaunchKernelGGL(k_crf, dim3(Bn), dim3(64), 0, stream, out_logits, labels, lens_i, trans, out_ll);
}

// Round 19
// 303.000 us; speedup vs baseline: 1.0784x; 1.0784x over previous
//
#include <hip/hip_runtime.h>
#include <hip/hip_bf16.h>

#define Bn 256
#define Tn 200
#define En 100
#define Hn 128
#define Kn 13
#define G4 512          // 4H
#define BT 51200        // B*T

typedef __attribute__((ext_vector_type(8))) __bf16 bf8_t;
typedef __attribute__((ext_vector_type(4))) float f4_t;

__device__ __forceinline__ unsigned short f2bf(float f) {
  unsigned int u = __float_as_uint(f);
  u = (u + 0x7FFFu + ((u >> 16) & 1u)) >> 16;
  return (unsigned short)u;
}
__device__ __forceinline__ float bf2f(unsigned short s) {
  return __uint_as_float(((unsigned int)s) << 16);
}
__device__ __forceinline__ float sigm(float x) { return 1.f / (1.f + __expf(-x)); }

// LDS-only barrier: drains lgkmcnt but lets VMEM stay in flight across it.
__device__ __forceinline__ void bar_lgkm() {
  asm volatile("s_waitcnt lgkmcnt(0)" ::: "memory");
  __builtin_amdgcn_s_barrier();
  __builtin_amdgcn_sched_barrier(0);
}

// Gate permutation: permuted col n holds original col g*128 + j with
// g=(n>>4)&3, j=(n>>6)*16+(n&15) -> gates i,f,g,o of unit j=w*16+lr land in
// one scan lane's 4 nt-accumulators (n = w*64+nt*16+lr).
__device__ __forceinline__ int gperm(int n) {
  return ((n >> 4) & 3) * 128 + ((n >> 6) << 4) + (n & 15);
}

#define MFMA(a, b, c) __builtin_amdgcn_mfma_f32_16x16x32_bf16(a, b, c, 0, 0, 0)

// ---------- prep: wt/ut (0..1023) + lens (1024..1087) + xg gather (1088..1487) ----------
__global__ __launch_bounds__(256) void k_prep(const int* __restrict__ text,
                                              const float* __restrict__ emb,
                                              const float* __restrict__ Wf,
                                              const float* __restrict__ Wb,
                                              const float* __restrict__ Uf,
                                              const float* __restrict__ Ub,
                                              unsigned short* __restrict__ wt,
                                              unsigned short* __restrict__ ut,
                                              unsigned short* __restrict__ xg,
                                              int* __restrict__ lens_i,
                                              float* __restrict__ out_lens) {
  int bx = blockIdx.x;
  if (bx < 1024) {
    int idx = bx * 256 + threadIdx.x;   // 0..262143
    int half = idx >> 17;               // 0:W  1:U
    int rem = idx & 131071;
    int dir = rem >> 16;
    int nk = rem & 65535;
    int n = nk >> 7, k = nk & 127;
    int mc = gperm(n);
    if (half == 0) {
      const float* W = dir ? Wb : Wf;
      wt[rem] = f2bf((k < En) ? W[k * G4 + mc] : 0.f);
    } else {
      const float* U = dir ? Ub : Uf;
      ut[rem] = f2bf(U[k * G4 + mc]);
    }
  } else if (bx < 1088) {
    int wi = threadIdx.x >> 6, lane = threadIdx.x & 63;
    int b = (bx - 1024) * 4 + wi;
    int cnt = 0;
    for (int t = lane; t < Tn; t += 64) cnt += (text[b * Tn + t] != 0);
    for (int off = 32; off; off >>= 1) cnt += __shfl_down(cnt, off);
    if (lane == 0) { lens_i[b] = cnt; out_lens[b] = (float)cnt; }
  } else {
    // xg[t][b][128] bf16: row = t*256 + b, tok = text[b*Tn + t]
    int row = (bx - 1088) * 128 + (threadIdx.x >> 1);
    int half = threadIdx.x & 1;
    int b = row & 255, t = row >> 8;
    int tok = text[(size_t)b * Tn + t];
    const float* er = emb + (size_t)tok * En;
    unsigned short* xr = xg + (size_t)row * 128 + half * 64;
    #pragma unroll
    for (int c = 0; c < 64; c += 2) {
      int col = half * 64 + c;
      float v0 = (col < En) ? er[col] : 0.f;
      float v1 = (col + 1 < En) ? er[col + 1] : 0.f;
      unsigned int pk = (unsigned int)f2bf(v0) | ((unsigned int)f2bf(v1) << 16);
      *(unsigned int*)(xr + c) = pk;
    }
  }
}

// ---------- fused recurrent scan (R19): 8 waves, x A-frags DIRECT FROM GLOBAL ----------
// R18 lesson: 4-wave consolidation halved LDS reads (conflicts 6.57M->3.28M,
// model confirmed) but killed wave-overlap (1 wave/SIMD, 2510 cyc/step).
// R19 keeps R17's 8-wave structure and instead deletes the x LDS path: the
// x@W A-frag only matters in rows {0,4,8,12} (the D-rows gates read), so each
// lane loads its frag straight from xg[t][b][128] bf16 (4 x 16B global loads,
// 2-step prefetch slack on the idle VMEM pipe). Removes 4 of 8 ds_reads/wave
// (-384 cyc/CU LDS pipe), the x publishes, and the in-scan emb gather.
#define FR16(M) M(0,0) M(0,1) M(0,2) M(0,3) M(1,0) M(1,1) M(1,2) M(1,3) \
                M(2,0) M(2,1) M(2,2) M(2,3) M(3,0) M(3,1) M(3,2) M(3,3)

__global__ __attribute__((amdgpu_flat_work_group_size(512, 512),
                          amdgpu_waves_per_eu(1, 2)))
void k_scan(const unsigned short* __restrict__ xg,
            const unsigned short* __restrict__ wt,
            const unsigned short* __restrict__ ut,
            const float* __restrict__ biasf,
            const float* __restrict__ biasb,
            unsigned short* __restrict__ hf,
            unsigned short* __restrict__ hb) {
  int blk = blockIdx.x;              // 0..127
  int dir = blk >> 6;
  int bg = blk & 63;
  int b0 = bg * 4;
  int tid = threadIdx.x;
  int w = tid >> 6, l = tid & 63;
  int lr = l & 15, lg = l >> 4;
  int jj = w * 16 + lr;
  const unsigned short* ut_d = ut + (size_t)dir * (G4 * 128);
  const unsigned short* wt_d = wt + (size_t)dir * (G4 * 128);
  const float* bias = dir ? biasb : biasf;
  unsigned short* hout = dir ? hb : hf;
  int t0 = dir ? (Tn - 1) : 0;
  int dt = dir ? -1 : 1;

  // U and W B-frags pinned into AGPRs (32 frags = 128 AGPR)
#define LOADUB(nt, kk) \
  bf8_t ub_##nt##_##kk = *(const bf8_t*)(ut_d + (size_t)(w * 64 + (nt) * 16 + lr) * 128 + (kk) * 32 + lg * 8); \
  asm volatile("" : "+a"(ub_##nt##_##kk));
  FR16(LOADUB)
#undef LOADUB
#define LOADWB(nt, kk) \
  bf8_t wb_##nt##_##kk = *(const bf8_t*)(wt_d + (size_t)(w * 64 + (nt) * 16 + lr) * 128 + (kk) * 32 + lg * 8); \
  asm volatile("" : "+a"(wb_##nt##_##kk));
  FR16(LOADWB)
#undef LOADWB

  // LDS: h double buffer only (2 x 4KB, XOR-swizzled rows)
  __shared__ __align__(16) char lds_all[8192];
  char* lbase = lds_all;
  for (int i = tid; i < 2048; i += 512) ((unsigned int*)lds_all)[i] = 0;

  // bias C-init vectors (constant for the whole loop)
  float bn0 = bias[gperm(w * 64 +  0 + lr)];
  float bn1 = bias[gperm(w * 64 + 16 + lr)];
  float bn2 = bias[gperm(w * 64 + 32 + lr)];
  float bn3 = bias[gperm(w * 64 + 48 + lr)];
  f4_t bv0 = {bn0, bn0, bn0, bn0};
  f4_t bv1 = {bn1, bn1, bn1, bn1};
  f4_t bv2 = {bn2, bn2, bn2, bn2};
  f4_t bv3 = {bn3, bn3, bn3, bn3};

  // x A-frag source row: lane lr in {0,4,8,12} maps to batch b0+lr/4 (real);
  // other lanes load a valid row, values land in unread D-rows (harmless).
  const unsigned short* xrow = xg + ((size_t)(b0 + (lr >> 2))) * 128 + lg * 8;
  const size_t xtstep = (size_t)Bn * 128;   // +1 in t

#define XLOAD(XF, TQ) { int tc = (TQ); tc = tc < 0 ? 0 : (tc > Tn - 1 ? Tn - 1 : tc); \
    const unsigned short* xp = xrow + (size_t)tc * xtstep; \
    XF##0 = *(const bf8_t*)(xp); \
    XF##1 = *(const bf8_t*)(xp + 32); \
    XF##2 = *(const bf8_t*)(xp + 64); \
    XF##3 = *(const bf8_t*)(xp + 96); }

  // h LDS addresses; read buf0 / write buf1, toggled by ^4096
  int rb0 = (lr * 256 +   0 + lg * 16) ^ ((lr & 7) << 4);
  int rb1 = (lr * 256 +  64 + lg * 16) ^ ((lr & 7) << 4);
  int rb2 = (lr * 256 + 128 + lg * 16) ^ ((lr & 7) << 4);
  int rb3 = (lr * 256 + 192 + lg * 16) ^ ((lr & 7) << 4);
  int wbh = (((lg * 4) * 256 + jj * 2) ^ (((lg * 4) & 7) << 4)) + 4096;

  unsigned short* hp = hout + ((size_t)t0 * Bn + b0 + lg) * 128 + jj;
  const long long hstep = (long long)dt * Bn * 128;

  // prologue: P = bias + x[t0]@W (frags direct from xg); prefetch xfA, xfB
  f4_t pA0, pA1, pA2, pA3;
  f4_t pB0, pB1, pB2, pB3;
  bf8_t xp0, xp1, xp2, xp3;
  XLOAD(xp, t0)
  pA0 = MFMA(xp0, wb_0_0, bv0);
  pA1 = MFMA(xp0, wb_1_0, bv1);
  pA2 = MFMA(xp0, wb_2_0, bv2);
  pA3 = MFMA(xp0, wb_3_0, bv3);
  pA0 = MFMA(xp1, wb_0_1, pA0);
  pA1 = MFMA(xp1, wb_1_1, pA1);
  pA2 = MFMA(xp1, wb_2_1, pA2);
  pA3 = MFMA(xp1, wb_3_1, pA3);
  pA0 = MFMA(xp2, wb_0_2, pA0);
  pA1 = MFMA(xp2, wb_1_2, pA1);
  pA2 = MFMA(xp2, wb_2_2, pA2);
  pA3 = MFMA(xp2, wb_3_2, pA3);
  pA0 = MFMA(xp3, wb_0_3, pA0);
  pA1 = MFMA(xp3, wb_1_3, pA1);
  pA2 = MFMA(xp3, wb_2_3, pA2);
  pA3 = MFMA(xp3, wb_3_3, pA3);
  bf8_t xfA0, xfA1, xfA2, xfA3;
  bf8_t xfB0, xfB1, xfB2, xfB3;
  XLOAD(xfA, t0 + dt)
  XLOAD(xfB, t0 + 2 * dt)
  float c0 = 0.f;
  int t = t0;
  bar_lgkm();                             // h zeros visible

  // STEP: gates from P (extended by h@U); Q = bias + x[t+dt]@W from XF;
  // then XF <- xg[t+3dt] (consumed 2 steps later).
#define STEPF(P, Q, XF) { \
    bf8_t af0 = *(const bf8_t*)(lbase + rb0); \
    bf8_t af1 = *(const bf8_t*)(lbase + rb1); \
    bf8_t af2 = *(const bf8_t*)(lbase + rb2); \
    bf8_t af3 = *(const bf8_t*)(lbase + rb3); \
    /* h@U extends P in place (P already = bias + x_t@W) */ \
    P##0 = MFMA(af0, ub_0_0, P##0); \
    P##1 = MFMA(af0, ub_1_0, P##1); \
    P##2 = MFMA(af0, ub_2_0, P##2); \
    P##3 = MFMA(af0, ub_3_0, P##3); \
    P##0 = MFMA(af1, ub_0_1, P##0); \
    P##1 = MFMA(af1, ub_1_1, P##1); \
    P##2 = MFMA(af1, ub_2_1, P##2); \
    P##3 = MFMA(af1, ub_3_1, P##3); \
    P##0 = MFMA(af2, ub_0_2, P##0); \
    P##1 = MFMA(af2, ub_1_2, P##1); \
    P##2 = MFMA(af2, ub_2_2, P##2); \
    P##3 = MFMA(af2, ub_3_2, P##3); \
    P##0 = MFMA(af3, ub_0_3, P##0); \
    P##1 = MFMA(af3, ub_1_3, P##1); \
    P##2 = MFMA(af3, ub_2_3, P##2); \
    P##3 = MFMA(af3, ub_3_3, P##3); \
    /* Q = bias + x[t+dt]@W from XF regs (off critical path) */ \
    Q##0 = MFMA(XF##0, wb_0_0, bv0); \
    Q##1 = MFMA(XF##0, wb_1_0, bv1); \
    Q##2 = MFMA(XF##0, wb_2_0, bv2); \
    Q##3 = MFMA(XF##0, wb_3_0, bv3); \
    Q##0 = MFMA(XF##1, wb_0_1, Q##0); \
    Q##1 = MFMA(XF##1, wb_1_1, Q##1); \
    Q##2 = MFMA(XF##1, wb_2_1, Q##2); \
    Q##3 = MFMA(XF##1, wb_3_1, Q##3); \
    Q##0 = MFMA(XF##2, wb_0_2, Q##0); \
    Q##1 = MFMA(XF##2, wb_1_2, Q##1); \
    Q##2 = MFMA(XF##2, wb_2_2, Q##2); \
    Q##3 = MFMA(XF##2, wb_3_2, Q##3); \
    Q##0 = MFMA(XF##3, wb_0_3, Q##0); \
    Q##1 = MFMA(XF##3, wb_1_3, Q##1); \
    Q##2 = MFMA(XF##3, wb_2_3, Q##2); \
    Q##3 = MFMA(XF##3, wb_3_3, Q##3); \
    /* refill XF for 2 steps ahead */ \
    XLOAD(XF, t + 3 * dt) \
    /* gates from P */ \
    float ig = sigm(P##0[0]); \
    float fg = sigm(P##1[0]); \
    float gg = fmaxf(P##2[0], 0.f); \
    c0 = fmaf(fg, c0, ig * gg); \
    unsigned short hs2 = f2bf(sigm(P##3[0]) * fmaxf(c0, 0.f)); \
    *(unsigned short*)(lbase + wbh) = hs2; \
    bar_lgkm(); \
    hp[0] = hs2; \
    rb0 ^= 4096; rb1 ^= 4096; rb2 ^= 4096; rb3 ^= 4096; \
    wbh ^= 4096; \
    hp += hstep; \
    t += dt; }

  for (int tt = 0; tt < Tn; tt += 2) {
    STEPF(pA, pB, xfA)
    STEPF(pB, pA, xfB)
  }
#undef STEPF
#undef XLOAD
}

// ---------- logits = softmax([hf|hb] @ Wd + bd); h rows are (t*Bn+b) ----------
__global__ __launch_bounds__(128) void k_logits(const unsigned short* __restrict__ hf,
                                                const unsigned short* __restrict__ hb,
                                                const float* __restrict__ Wd,
                                                const float* __restrict__ bd,
                                                float* __restrict__ out) {
  __shared__ unsigned short hs[128 * 256];   // 64KB, XOR-swizzled rows of 512B
  int tid = threadIdx.x;
  size_t row0 = (size_t)blockIdx.x * 128;
  #pragma unroll
  for (int it = 0; it < 16; it++) {
    int idx = it * 128 + tid;
    int r = idx >> 4, c = idx & 15;
    bf8_t vf = *(const bf8_t*)(hf + (row0 + r) * 128 + c * 8);
    bf8_t vb = *(const bf8_t*)(hb + (row0 + r) * 128 + c * 8);
    int byte = (r * 512 + c * 16) ^ ((r & 7) << 4);
    *(bf8_t*)((char*)hs + byte) = vf;
    int byte2 = (r * 512 + 256 + c * 16) ^ ((r & 7) << 4);
    *(bf8_t*)((char*)hs + byte2) = vb;
  }
  __syncthreads();
  float acc[Kn];
  #pragma unroll
  for (int jj = 0; jj < Kn; jj++) acc[jj] = bd[jj];
  int r = tid;
  #pragma unroll 4
  for (int c = 0; c < 32; c++) {
    int byte = (r * 512 + c * 16) ^ ((r & 7) << 4);
    bf8_t v = *(const bf8_t*)((const char*)hs + byte);
    #pragma unroll
    for (int e = 0; e < 8; e++) {
      float h = (float)v[e];
      int k = c * 8 + e;
      #pragma unroll
      for (int jj = 0; jj < Kn; jj++)
        acc[jj] = fmaf(h, Wd[k * Kn + jj], acc[jj]);   // uniform -> scalar loads
    }
  }
  float m = acc[0];
  #pragma unroll
  for (int jj = 1; jj < Kn; jj++) m = fmaxf(m, acc[jj]);
  float s = 0.f;
  #pragma unroll
  for (int jj = 0; jj < Kn; jj++) { acc[jj] = __expf(acc[jj] - m); s += acc[jj]; }
  float inv = 1.f / s;
  int rg = (int)row0 + tid;          // h row index = t*Bn + b
  int b = rg & 255, t = rg >> 8;
  float* op = out + ((size_t)b * Tn + t) * Kn;
  #pragma unroll
  for (int jj = 0; jj < Kn; jj++) op[jj] = acc[jj] * inv;
}

// ---------- CRF log-likelihood: one wave per batch row ----------
__global__ __launch_bounds__(64) void k_crf(const float* __restrict__ logits,
                                            const int* __restrict__ labels,
                                            const int* __restrict__ lens_i,
                                            const float* __restrict__ trans,
                                            float* __restrict__ out_ll) {
  int b = blockIdx.x, lane = threadIdx.x;
  int len = lens_i[b];
  const float* lg = logits + (size_t)b * Tn * Kn;
  const int* lab = labels + (size_t)b * Tn;
  float sc = 0.f;
  for (int t = lane; t < Tn; t += 64) {
    if (t < len) {
      sc += lg[t * Kn + lab[t]];
      if (t >= 1) sc += trans[lab[t - 1] * Kn + lab[t]];
    }
  }
  for (int off = 32; off; off >>= 1) sc += __shfl_down(sc, off);
  bool act = lane < Kn;
  int jl = act ? lane : 0;
  float etr[Kn];
  #pragma unroll
  for (int i = 0; i < Kn; i++) etr[i] = __expf(trans[i * Kn + jl]);
  float a = act ? lg[jl] : -INFINITY;
  float lgv = (len > 1) ? lg[Kn + jl] : 0.f;
  for (int t = 1; t < len; t++) {
    float lgn = (t + 1 < len) ? lg[(t + 1) * Kn + jl] : 0.f;
    float m = a;
    for (int off = 8; off; off >>= 1) m = fmaxf(m, __shfl_xor(m, off, 16));
    float ea = __expf(a - m);
    float s = 0.f;
    #pragma unroll
    for (int i = 0; i < Kn; i++) s = fmaf(__shfl(ea, i), etr[i], s);
    float anew = m + __logf(s) + lgv;
    if (act) a = anew;
    lgv = lgn;
  }
  float m2 = a;
  for (int off = 8; off; off >>= 1) m2 = fmaxf(m2, __shfl_xor(m2, off, 16));
  float ea2 = act ? __expf(a - m2) : 0.f;
  float ssum = ea2;
  for (int off = 8; off; off >>= 1) ssum += __shfl_xor(ssum, off, 16);
  float logZ = m2 + __logf(ssum);
  if (lane == 0) out_ll[b] = sc - logZ;
}

extern "C" void kernel_launch(void* const* d_in, const int* in_sizes, int n_in,
                              void* d_out, int out_size, void* d_ws, size_t ws_size,
                              hipStream_t stream) {
  const int* text = (const int*)d_in[0];
  const int* labels = (const int*)d_in[1];
  const float* emb = (const float*)d_in[2];
  const float* Wf = (const float*)d_in[3];
  const float* Uf = (const float*)d_in[4];
  const float* bf_ = (const float*)d_in[5];
  const float* Wb = (const float*)d_in[6];
  const float* Ub = (const float*)d_in[7];
  const float* bb_ = (const float*)d_in[8];
  const float* Wd = (const float*)d_in[9];
  const float* bd = (const float*)d_in[10];
  const float* trans = (const float*)d_in[11];
  (void)in_sizes; (void)n_in; (void)out_size; (void)ws_size;

  float* out = (float*)d_out;
  float* out_logits = out;                       // [BT*K]
  float* out_lens = out + (size_t)BT * Kn;       // [B]
  float* out_ll = out_lens + Bn;                 // [B]

  char* ws = (char*)d_ws;
  size_t o = 0;
  int* lens_i = (int*)(ws + o);                o += 1024;
  unsigned short* wt = (unsigned short*)(ws + o);  o += (size_t)2 * G4 * 128 * 2;
  unsigned short* ut = (unsigned short*)(ws + o);  o += (size_t)2 * G4 * 128 * 2;
  unsigned short* xg = (unsigned short*)(ws + o);  o += (size_t)BT * 128 * 2;      // [t][b][128]
  unsigned short* hfb = (unsigned short*)(ws + o); o += (size_t)BT * Hn * 2;       // [t][b][128]
  unsigned short* hbb = (unsigned short*)(ws + o); o += (size_t)BT * Hn * 2;

  hipLaunchKernelGGL(k_prep, dim3(1488), dim3(256), 0, stream,
                     text, emb, Wf, Wb, Uf, Ub, wt, ut, xg, lens_i, out_lens);
  hipLaunchKernelGGL(k_scan, dim3(128), dim3(512), 0, stream,
                     xg, wt, ut, bf_, bb_, hfb, hbb);
  hipLaunchKernelGGL(k_logits, dim3(400), dim3(128), 0, stream, hfb, hbb, Wd, bd, out_logits);
  hipLaunchKernelGGL(k_crf, dim3(Bn), dim3(64), 0, stream, out_logits, labels, lens_i, trans, out_ll);
}

// Round 20
// 294.190 us; speedup vs baseline: 1.1107x; 1.0299x over previous
//
#include <hip/hip_runtime.h>
#include <hip/hip_bf16.h>

#define Bn 256
#define Tn 200
#define En 100
#define Hn 128
#define Kn 13
#define G4 512          // 4H
#define BT 51200        // B*T

typedef __attribute__((ext_vector_type(8))) __bf16 bf8_t;
typedef __attribute__((ext_vector_type(4))) float f4_t;

__device__ __forceinline__ unsigned short f2bf(float f) {
  unsigned int u = __float_as_uint(f);
  u = (u + 0x7FFFu + ((u >> 16) & 1u)) >> 16;
  return (unsigned short)u;
}
__device__ __forceinline__ float bf2f(unsigned short s) {
  return __uint_as_float(((unsigned int)s) << 16);
}
__device__ __forceinline__ float sigm(float x) { return 1.f / (1.f + __expf(-x)); }

// LDS-only barrier: drains lgkmcnt but lets VMEM stay in flight across it.
// R20: sched_barrier(0) REMOVED (m141: order-pinning defeats the scheduler;
// rule-18 hazard absent since all ds_reads are compiler-emitted).
__device__ __forceinline__ void bar_lgkm() {
  asm volatile("s_waitcnt lgkmcnt(0)" ::: "memory");
  __builtin_amdgcn_s_barrier();
}

// Gate permutation: permuted col n holds original col g*128 + j with
// g=(n>>4)&3, j=(n>>6)*16+(n&15) -> gates i,f,g,o of unit j=w*16+lr land in
// one scan lane's 4 nt-accumulators (n = w*64+nt*16+lr).
__device__ __forceinline__ int gperm(int n) {
  return ((n >> 4) & 3) * 128 + ((n >> 6) << 4) + (n & 15);
}

#define MFMA(a, b, c) __builtin_amdgcn_mfma_f32_16x16x32_bf16(a, b, c, 0, 0, 0)

// ---------- prep: wt/ut transpose-permute (blocks 0..1023) + lens (1024..1087) ----------
__global__ __launch_bounds__(256) void k_prep(const int* __restrict__ text,
                                              const float* __restrict__ Wf,
                                              const float* __restrict__ Wb,
                                              const float* __restrict__ Uf,
                                              const float* __restrict__ Ub,
                                              unsigned short* __restrict__ wt,
                                              unsigned short* __restrict__ ut,
                                              int* __restrict__ lens_i,
                                              float* __restrict__ out_lens) {
  int bx = blockIdx.x;
  if (bx < 1024) {
    int idx = bx * 256 + threadIdx.x;   // 0..262143
    int half = idx >> 17;               // 0:W  1:U
    int rem = idx & 131071;
    int dir = rem >> 16;
    int nk = rem & 65535;
    int n = nk >> 7, k = nk & 127;
    int mc = gperm(n);
    if (half == 0) {
      const float* W = dir ? Wb : Wf;
      wt[rem] = f2bf((k < En) ? W[k * G4 + mc] : 0.f);
    } else {
      const float* U = dir ? Ub : Uf;
      ut[rem] = f2bf(U[k * G4 + mc]);
    }
  } else {
    int wi = threadIdx.x >> 6, lane = threadIdx.x & 63;
    int b = (bx - 1024) * 4 + wi;
    int cnt = 0;
    for (int t = lane; t < Tn; t += 64) cnt += (text[b * Tn + t] != 0);
    for (int off = 32; off; off >>= 1) cnt += __shfl_down(cnt, off);
    if (lane == 0) { lens_i[b] = cnt; out_lens[b] = (float)cnt; }
  }
}

// ---------- fused recurrent scan (R20 = R17 + unpinned barrier + 2+2 U-chains) ----------
// R19 proved the x-path (ds_reads/publish/gather) is OFF the critical path
// (removing it all: 167.6 -> 167.3). The invariant is the sync phase:
// bar -> ds_read h -> 4-deep dependent U-MFMA chains -> gates -> write -> bar.
// R20 halves the exposed dependent-MFMA depth (two 2-deep chains, gates read
// P[0]+B[0]) and unpins the barrier so Q/gather work can fill the stall.
#define FR16(M) M(0,0) M(0,1) M(0,2) M(0,3) M(1,0) M(1,1) M(1,2) M(1,3) \
                M(2,0) M(2,1) M(2,2) M(2,3) M(3,0) M(3,1) M(3,2) M(3,3)

__global__ __attribute__((amdgpu_flat_work_group_size(512, 512),
                          amdgpu_waves_per_eu(1, 2)))
void k_scan(const int* __restrict__ text,
            const float* __restrict__ emb,
            const unsigned short* __restrict__ wt,
            const unsigned short* __restrict__ ut,
            const float* __restrict__ biasf,
            const float* __restrict__ biasb,
            unsigned short* __restrict__ hf,
            unsigned short* __restrict__ hb) {
  int blk = blockIdx.x;              // 0..127
  int dir = blk >> 6;
  int bg = blk & 63;
  int b0 = bg * 4;
  int tid = threadIdx.x;
  int w = tid >> 6, l = tid & 63;
  int lr = l & 15, lg = l >> 4;
  int jj = w * 16 + lr;
  const unsigned short* ut_d = ut + (size_t)dir * (G4 * 128);
  const unsigned short* wt_d = wt + (size_t)dir * (G4 * 128);
  const float* bias = dir ? biasb : biasf;
  unsigned short* hout = dir ? hb : hf;
  int t0 = dir ? (Tn - 1) : 0;
  int dt = dir ? -1 : 1;

  // U and W B-frags pinned into AGPRs (32 frags = 128 AGPR)
#define LOADUB(nt, kk) \
  bf8_t ub_##nt##_##kk = *(const bf8_t*)(ut_d + (size_t)(w * 64 + (nt) * 16 + lr) * 128 + (kk) * 32 + lg * 8); \
  asm volatile("" : "+a"(ub_##nt##_##kk));
  FR16(LOADUB)
#undef LOADUB
#define LOADWB(nt, kk) \
  bf8_t wb_##nt##_##kk = *(const bf8_t*)(wt_d + (size_t)(w * 64 + (nt) * 16 + lr) * 128 + (kk) * 32 + lg * 8); \
  asm volatile("" : "+a"(wb_##nt##_##kk));
  FR16(LOADWB)
#undef LOADWB

  // LDS: h dbuf [0,8K) ; x dbuf [8K,16K) ; tokens [16K,16K+3200)
  __shared__ __align__(16) char lds_all[16384 + Tn * 4 * 4];
  char* lbase = lds_all;
  int* tl = (int*)(lds_all + 16384);
  for (int i = tid; i < 4096; i += 512) ((unsigned int*)lds_all)[i] = 0;
  #pragma unroll
  for (int r = 0; r < 4; r++)
    if (tid < Tn) tl[r * Tn + tid] = text[(size_t)(b0 + r) * Tn + tid];

  // bias C-init vectors (constant for the whole loop)
  float bn0 = bias[gperm(w * 64 +  0 + lr)];
  float bn1 = bias[gperm(w * 64 + 16 + lr)];
  float bn2 = bias[gperm(w * 64 + 32 + lr)];
  float bn3 = bias[gperm(w * 64 + 48 + lr)];
  f4_t bv0 = {bn0, bn0, bn0, bn0};
  f4_t bv1 = {bn1, bn1, bn1, bn1};
  f4_t bv2 = {bn2, bn2, bn2, bn2};
  f4_t bv3 = {bn3, bn3, bn3, bn3};
  const f4_t z4 = {0.f, 0.f, 0.f, 0.f};

  // x gather duty: thread covers (xrow, xcol)
  int xrow = tid >> 7;               // 0..3
  int xcol = tid & 127;
  bool xon = (xcol < En);
  // prologue x values: x[t0], x[t0+dt], x[t0+2dt], x[t0+3dt]
  float v0 = 0.f, v1 = 0.f, vA = 0.f, vB = 0.f;
  {
    const int* trow = text + (size_t)(b0 + xrow) * Tn;
    int k0 = trow[t0], k1 = trow[t0 + dt], k2 = trow[t0 + 2 * dt], k3 = trow[t0 + 3 * dt];
    if (xon) {
      v0 = emb[(size_t)k0 * En + xcol];
      v1 = emb[(size_t)k1 * En + xcol];
      vA = emb[(size_t)k2 * En + xcol];
      vB = emb[(size_t)k3 * En + xcol];
    }
  }

  // LDS addresses; h: read buf0 / write buf1; x: read bufB / write bufA
  int rb0 = (lr * 256 +   0 + lg * 16) ^ ((lr & 7) << 4);
  int rb1 = (lr * 256 +  64 + lg * 16) ^ ((lr & 7) << 4);
  int rb2 = (lr * 256 + 128 + lg * 16) ^ ((lr & 7) << 4);
  int rb3 = (lr * 256 + 192 + lg * 16) ^ ((lr & 7) << 4);
  int xb0 = 12288 + rb0, xb1 = 12288 + rb1, xb2 = 12288 + rb2, xb3 = 12288 + rb3;
  int wbh = (((lg * 4) * 256 + jj * 2) ^ (((lg * 4) & 7) << 4)) + 4096;
  int wbx = 8192 + (((xrow * 4) * 256 + xcol * 2) ^ (((xrow * 4) & 7) << 4));

  unsigned short* hp = hout + ((size_t)t0 * Bn + b0 + lg) * 128 + jj;
  const long long hstep = (long long)dt * Bn * 128;

  // publish x[t0] -> bufA, x[t0+dt] -> bufB
  *(unsigned short*)(lbase + wbx) = f2bf(v0);
  *(unsigned short*)(lbase + (wbx ^ 4096)) = f2bf(v1);
  bar_lgkm();                             // zeros + tokens + x publishes visible

  // prologue: P = bias + x[t0]@W (reads bufA frags)
  f4_t pA0 = bv0, pA1 = bv1, pA2 = bv2, pA3 = bv3;
  f4_t pB0, pB1, pB2, pB3;
  {
    bf8_t ax0 = *(const bf8_t*)(lbase + 8192 + rb0);
    bf8_t ax1 = *(const bf8_t*)(lbase + 8192 + rb1);
    bf8_t ax2 = *(const bf8_t*)(lbase + 8192 + rb2);
    bf8_t ax3 = *(const bf8_t*)(lbase + 8192 + rb3);
#define MFP(nt, kk) pA##nt = MFMA(ax##kk, wb_##nt##_##kk, pA##nt);
    MFP(0,0) MFP(1,0) MFP(2,0) MFP(3,0)
    MFP(0,1) MFP(1,1) MFP(2,1) MFP(3,1)
    MFP(0,2) MFP(1,2) MFP(2,2) MFP(3,2)
    MFP(0,3) MFP(1,3) MFP(2,3) MFP(3,3)
#undef MFP
  }
  float c0 = 0.f;
  int t = t0;

  // STEP(P, Q): gates from P+B (U split into two 2-deep chains); Q = bias +
  // x[t+1]@W for next step.
#define STEPF(P, Q) { \
    bf8_t af0 = *(const bf8_t*)(lbase + rb0); \
    bf8_t af1 = *(const bf8_t*)(lbase + rb1); \
    bf8_t af2 = *(const bf8_t*)(lbase + rb2); \
    bf8_t af3 = *(const bf8_t*)(lbase + rb3); \
    /* publish x[t+2]; rotate pipeline; load x[t+3] */ \
    *(unsigned short*)(lbase + wbx) = f2bf(vA); \
    vA = vB; \
    { int tc = t + 3 * dt; tc = tc < 0 ? 0 : (tc > Tn - 1 ? Tn - 1 : tc); \
      int tokN = tl[xrow * Tn + tc]; \
      vB = xon ? emb[(size_t)tokN * En + xcol] : 0.f; } \
    /* h@U as two 2-deep chains: P extends (kk0,kk1); B fresh (kk2,kk3) */ \
    f4_t B0, B1, B2, B3; \
    P##0 = MFMA(af0, ub_0_0, P##0); \
    P##1 = MFMA(af0, ub_1_0, P##1); \
    P##2 = MFMA(af0, ub_2_0, P##2); \
    P##3 = MFMA(af0, ub_3_0, P##3); \
    B0 = MFMA(af2, ub_0_2, z4); \
    B1 = MFMA(af2, ub_1_2, z4); \
    B2 = MFMA(af2, ub_2_2, z4); \
    B3 = MFMA(af2, ub_3_2, z4); \
    P##0 = MFMA(af1, ub_0_1, P##0); \
    P##1 = MFMA(af1, ub_1_1, P##1); \
    P##2 = MFMA(af1, ub_2_1, P##2); \
    P##3 = MFMA(af1, ub_3_1, P##3); \
    B0 = MFMA(af3, ub_0_3, B0); \
    B1 = MFMA(af3, ub_1_3, B1); \
    B2 = MFMA(af3, ub_2_3, B2); \
    B3 = MFMA(af3, ub_3_3, B3); \
    /* x[t+1]@W into Q (off critical path) */ \
    { bf8_t ax0 = *(const bf8_t*)(lbase + xb0); \
      bf8_t ax1 = *(const bf8_t*)(lbase + xb1); \
      bf8_t ax2 = *(const bf8_t*)(lbase + xb2); \
      bf8_t ax3 = *(const bf8_t*)(lbase + xb3); \
      Q##0 = bv0; Q##1 = bv1; Q##2 = bv2; Q##3 = bv3; \
      Q##0 = MFMA(ax0, wb_0_0, Q##0); \
      Q##1 = MFMA(ax0, wb_1_0, Q##1); \
      Q##2 = MFMA(ax0, wb_2_0, Q##2); \
      Q##3 = MFMA(ax0, wb_3_0, Q##3); \
      Q##0 = MFMA(ax1, wb_0_1, Q##0); \
      Q##1 = MFMA(ax1, wb_1_1, Q##1); \
      Q##2 = MFMA(ax1, wb_2_1, Q##2); \
      Q##3 = MFMA(ax1, wb_3_1, Q##3); \
      Q##0 = MFMA(ax2, wb_0_2, Q##0); \
      Q##1 = MFMA(ax2, wb_1_2, Q##1); \
      Q##2 = MFMA(ax2, wb_2_2, Q##2); \
      Q##3 = MFMA(ax2, wb_3_2, Q##3); \
      Q##0 = MFMA(ax3, wb_0_3, Q##0); \
      Q##1 = MFMA(ax3, wb_1_3, Q##1); \
      Q##2 = MFMA(ax3, wb_2_3, Q##2); \
      Q##3 = MFMA(ax3, wb_3_3, Q##3); } \
    /* gates from P + B */ \
    float zi = P##0[0] + B0[0]; \
    float zf = P##1[0] + B1[0]; \
    float zg = P##2[0] + B2[0]; \
    float zo = P##3[0] + B3[0]; \
    float ig = sigm(zi); \
    float fg = sigm(zf); \
    float gg = fmaxf(zg, 0.f); \
    c0 = fmaf(fg, c0, ig * gg); \
    unsigned short hs2 = f2bf(sigm(zo) * fmaxf(c0, 0.f)); \
    *(unsigned short*)(lbase + wbh) = hs2; \
    bar_lgkm(); \
    hp[0] = hs2; \
    rb0 ^= 4096; rb1 ^= 4096; rb2 ^= 4096; rb3 ^= 4096; \
    xb0 ^= 4096; xb1 ^= 4096; xb2 ^= 4096; xb3 ^= 4096; \
    wbh ^= 4096; wbx ^= 4096; \
    hp += hstep; \
    t += dt; }

  for (int tt = 0; tt < Tn; tt += 2) {
    STEPF(pA, pB)
    STEPF(pB, pA)
  }
#undef STEPF
}

// ---------- logits = softmax([hf|hb] @ Wd + bd); h rows are (t*Bn+b) ----------
__global__ __launch_bounds__(128) void k_logits(const unsigned short* __restrict__ hf,
                                                const unsigned short* __restrict__ hb,
                                                const float* __restrict__ Wd,
                                                const float* __restrict__ bd,
                                                float* __restrict__ out) {
  __shared__ unsigned short hs[128 * 256];   // 64KB, XOR-swizzled rows of 512B
  int tid = threadIdx.x;
  size_t row0 = (size_t)blockIdx.x * 128;
  #pragma unroll
  for (int it = 0; it < 16; it++) {
    int idx = it * 128 + tid;
    int r = idx >> 4, c = idx & 15;
    bf8_t vf = *(const bf8_t*)(hf + (row0 + r) * 128 + c * 8);
    bf8_t vb = *(const bf8_t*)(hb + (row0 + r) * 128 + c * 8);
    int byte = (r * 512 + c * 16) ^ ((r & 7) << 4);
    *(bf8_t*)((char*)hs + byte) = vf;
    int byte2 = (r * 512 + 256 + c * 16) ^ ((r & 7) << 4);
    *(bf8_t*)((char*)hs + byte2) = vb;
  }
  __syncthreads();
  float acc[Kn];
  #pragma unroll
  for (int jj = 0; jj < Kn; jj++) acc[jj] = bd[jj];
  int r = tid;
  #pragma unroll 4
  for (int c = 0; c < 32; c++) {
    int byte = (r * 512 + c * 16) ^ ((r & 7) << 4);
    bf8_t v = *(const bf8_t*)((const char*)hs + byte);
    #pragma unroll
    for (int e = 0; e < 8; e++) {
      float h = (float)v[e];
      int k = c * 8 + e;
      #pragma unroll
      for (int jj = 0; jj < Kn; jj++)
        acc[jj] = fmaf(h, Wd[k * Kn + jj], acc[jj]);   // uniform -> scalar loads
    }
  }
  float m = acc[0];
  #pragma unroll
  for (int jj = 1; jj < Kn; jj++) m = fmaxf(m, acc[jj]);
  float s = 0.f;
  #pragma unroll
  for (int jj = 0; jj < Kn; jj++) { acc[jj] = __expf(acc[jj] - m); s += acc[jj]; }
  float inv = 1.f / s;
  int rg = (int)row0 + tid;          // h row index = t*Bn + b
  int b = rg & 255, t = rg >> 8;
  float* op = out + ((size_t)b * Tn + t) * Kn;
  #pragma unroll
  for (int jj = 0; jj < Kn; jj++) op[jj] = acc[jj] * inv;
}

// ---------- CRF log-likelihood: one wave per batch row ----------
__global__ __launch_bounds__(64) void k_crf(const float* __restrict__ logits,
                                            const int* __restrict__ labels,
                                            const int* __restrict__ lens_i,
                                            const float* __restrict__ trans,
                                            float* __restrict__ out_ll) {
  int b = blockIdx.x, lane = threadIdx.x;
  int len = lens_i[b];
  const float* lg = logits + (size_t)b * Tn * Kn;
  const int* lab = labels + (size_t)b * Tn;
  float sc = 0.f;
  for (int t = lane; t < Tn; t += 64) {
    if (t < len) {
      sc += lg[t * Kn + lab[t]];
      if (t >= 1) sc += trans[lab[t - 1] * Kn + lab[t]];
    }
  }
  for (int off = 32; off; off >>= 1) sc += __shfl_down(sc, off);
  bool act = lane < Kn;
  int jl = act ? lane : 0;
  float etr[Kn];
  #pragma unroll
  for (int i = 0; i < Kn; i++) etr[i] = __expf(trans[i * Kn + jl]);
  float a = act ? lg[jl] : -INFINITY;
  float lgv = (len > 1) ? lg[Kn + jl] : 0.f;
  for (int t = 1; t < len; t++) {
    float lgn = (t + 1 < len) ? lg[(t + 1) * Kn + jl] : 0.f;
    float m = a;
    for (int off = 8; off; off >>= 1) m = fmaxf(m, __shfl_xor(m, off, 16));
    float ea = __expf(a - m);
    float s = 0.f;
    #pragma unroll
    for (int i = 0; i < Kn; i++) s = fmaf(__shfl(ea, i), etr[i], s);
    float anew = m + __logf(s) + lgv;
    if (act) a = anew;
    lgv = lgn;
  }
  float m2 = a;
  for (int off = 8; off; off >>= 1) m2 = fmaxf(m2, __shfl_xor(m2, off, 16));
  float ea2 = act ? __expf(a - m2) : 0.f;
  float ssum = ea2;
  for (int off = 8; off; off >>= 1) ssum += __shfl_xor(ssum, off, 16);
  float logZ = m2 + __logf(ssum);
  if (lane == 0) out_ll[b] = sc - logZ;
}

extern "C" void kernel_launch(void* const* d_in, const int* in_sizes, int n_in,
                              void* d_out, int out_size, void* d_ws, size_t ws_size,
                              hipStream_t stream) {
  const int* text = (const int*)d_in[0];
  const int* labels = (const int*)d_in[1];
  const float* emb = (const float*)d_in[2];
  const float* Wf = (const float*)d_in[3];
  const float* Uf = (const float*)d_in[4];
  const float* bf_ = (const float*)d_in[5];
  const float* Wb = (const float*)d_in[6];
  const float* Ub = (const float*)d_in[7];
  const float* bb_ = (const float*)d_in[8];
  const float* Wd = (const float*)d_in[9];
  const float* bd = (const float*)d_in[10];
  const float* trans = (const float*)d_in[11];
  (void)in_sizes; (void)n_in; (void)out_size; (void)ws_size;

  float* out = (float*)d_out;
  float* out_logits = out;                       // [BT*K]
  float* out_lens = out + (size_t)BT * Kn;       // [B]
  float* out_ll = out_lens + Bn;                 // [B]

  char* ws = (char*)d_ws;
  size_t o = 0;
  int* lens_i = (int*)(ws + o);                o += 1024;
  unsigned short* wt = (unsigned short*)(ws + o);  o += (size_t)2 * G4 * 128 * 2;
  unsigned short* ut = (unsigned short*)(ws + o);  o += (size_t)2 * G4 * 128 * 2;
  unsigned short* hfb = (unsigned short*)(ws + o); o += (size_t)BT * Hn * 2;       // [t][b][128]
  unsigned short* hbb = (unsigned short*)(ws + o); o += (size_t)BT * Hn * 2;

  hipLaunchKernelGGL(k_prep, dim3(1088), dim3(256), 0, stream,
                     text, Wf, Wb, Uf, Ub, wt, ut, lens_i, out_lens);
  hipLaunchKernelGGL(k_scan, dim3(128), dim3(512), 0, stream,
                     text, emb, wt, ut, bf_, bb_, hfb, hbb);
  hipLaunchKernelGGL(k_logits, dim3(400), dim3(128), 0, stream, hfb, hbb, Wd, bd, out_logits);
  hipLaunchKernelGGL(k_crf, dim3(Bn), dim3(64), 0, stream, out_logits, labels, lens_i, trans, out_ll);
}

// Round 21
// 265.831 us; speedup vs baseline: 1.2292x; 1.1067x over previous
//
#include <hip/hip_runtime.h>
#include <hip/hip_bf16.h>

#define Bn 256
#define Tn 200
#define En 100
#define Hn 128
#define Kn 13
#define G4 512          // 4H
#define BT 51200        // B*T

typedef __attribute__((ext_vector_type(8))) __bf16 bf8_t;
typedef __attribute__((ext_vector_type(4))) float f4_t;

__device__ __forceinline__ unsigned short f2bf(float f) {
  unsigned int u = __float_as_uint(f);
  u = (u + 0x7FFFu + ((u >> 16) & 1u)) >> 16;
  return (unsigned short)u;
}
__device__ __forceinline__ float bf2f(unsigned short s) {
  return __uint_as_float(((unsigned int)s) << 16);
}
__device__ __forceinline__ float sigm(float x) { return 1.f / (1.f + __expf(-x)); }

// LDS-only barrier (R17 form, sched_barrier kept: its removal in R20 regressed).
__device__ __forceinline__ void bar_lgkm() {
  asm volatile("s_waitcnt lgkmcnt(0)" ::: "memory");
  __builtin_amdgcn_s_barrier();
  __builtin_amdgcn_sched_barrier(0);
}

// Gate permutation: permuted col n holds original col g*128 + j with
// g=(n>>4)&3, j=(n>>6)*16+(n&15) -> gates i,f,g,o of unit j=w*16+lr land in
// one scan lane's 4 nt-accumulators (n = w*64+nt*16+lr).
__device__ __forceinline__ int gperm(int n) {
  return ((n >> 4) & 3) * 128 + ((n >> 6) << 4) + (n & 15);
}

// ---------- prep: wt/ut transpose-permute (blocks 0..1023) + lens (1024..1087) ----------
__global__ __launch_bounds__(256) void k_prep(const int* __restrict__ text,
                                              const float* __restrict__ Wf,
                                              const float* __restrict__ Wb,
                                              const float* __restrict__ Uf,
                                              const float* __restrict__ Ub,
                                              unsigned short* __restrict__ wt,
                                              unsigned short* __restrict__ ut,
                                              int* __restrict__ lens_i,
                                              float* __restrict__ out_lens) {
  int bx = blockIdx.x;
  if (bx < 1024) {
    int idx = bx * 256 + threadIdx.x;   // 0..262143
    int half = idx >> 17;               // 0:W  1:U
    int rem = idx & 131071;
    int dir = rem >> 16;
    int nk = rem & 65535;
    int n = nk >> 7, k = nk & 127;
    int mc = gperm(n);
    if (half == 0) {
      const float* W = dir ? Wb : Wf;
      wt[rem] = f2bf((k < En) ? W[k * G4 + mc] : 0.f);
    } else {
      const float* U = dir ? Ub : Uf;
      ut[rem] = f2bf(U[k * G4 + mc]);
    }
  } else {
    int wi = threadIdx.x >> 6, lane = threadIdx.x & 63;
    int b = (bx - 1024) * 4 + wi;
    int cnt = 0;
    for (int t = lane; t < Tn; t += 64) cnt += (text[b * Tn + t] != 0);
    for (int off = 32; off; off >>= 1) cnt += __shfl_down(cnt, off);
    if (lane == 0) { lens_i[b] = cnt; out_lens[b] = (float)cnt; }
  }
}

// ---------- fused recurrent scan (R17 exact — frozen; 167.6us measured) ----------
#define FR16(M) M(0,0) M(0,1) M(0,2) M(0,3) M(1,0) M(1,1) M(1,2) M(1,3) \
                M(2,0) M(2,1) M(2,2) M(2,3) M(3,0) M(3,1) M(3,2) M(3,3)

__global__ __attribute__((amdgpu_flat_work_group_size(512, 512),
                          amdgpu_waves_per_eu(1, 2)))
void k_scan(const int* __restrict__ text,
            const float* __restrict__ emb,
            const unsigned short* __restrict__ wt,
            const unsigned short* __restrict__ ut,
            const float* __restrict__ biasf,
            const float* __restrict__ biasb,
            unsigned short* __restrict__ hf,
            unsigned short* __restrict__ hb) {
  int blk = blockIdx.x;              // 0..127
  int dir = blk >> 6;
  int bg = blk & 63;
  int b0 = bg * 4;
  int tid = threadIdx.x;
  int w = tid >> 6, l = tid & 63;
  int lr = l & 15, lg = l >> 4;
  int jj = w * 16 + lr;
  const unsigned short* ut_d = ut + (size_t)dir * (G4 * 128);
  const unsigned short* wt_d = wt + (size_t)dir * (G4 * 128);
  const float* bias = dir ? biasb : biasf;
  unsigned short* hout = dir ? hb : hf;
  int t0 = dir ? (Tn - 1) : 0;
  int dt = dir ? -1 : 1;

  // U and W B-frags pinned into AGPRs (32 frags = 128 AGPR)
#define LOADUB(nt, kk) \
  bf8_t ub_##nt##_##kk = *(const bf8_t*)(ut_d + (size_t)(w * 64 + (nt) * 16 + lr) * 128 + (kk) * 32 + lg * 8); \
  asm volatile("" : "+a"(ub_##nt##_##kk));
  FR16(LOADUB)
#undef LOADUB
#define LOADWB(nt, kk) \
  bf8_t wb_##nt##_##kk = *(const bf8_t*)(wt_d + (size_t)(w * 64 + (nt) * 16 + lr) * 128 + (kk) * 32 + lg * 8); \
  asm volatile("" : "+a"(wb_##nt##_##kk));
  FR16(LOADWB)
#undef LOADWB

  // LDS: h dbuf [0,8K) ; x dbuf [8K,16K) ; tokens [16K,16K+3200)
  __shared__ __align__(16) char lds_all[16384 + Tn * 4 * 4];
  char* lbase = lds_all;
  int* tl = (int*)(lds_all + 16384);
  for (int i = tid; i < 4096; i += 512) ((unsigned int*)lds_all)[i] = 0;
  #pragma unroll
  for (int r = 0; r < 4; r++)
    if (tid < Tn) tl[r * Tn + tid] = text[(size_t)(b0 + r) * Tn + tid];

  // bias C-init vectors (constant for the whole loop)
  float bn0 = bias[gperm(w * 64 +  0 + lr)];
  float bn1 = bias[gperm(w * 64 + 16 + lr)];
  float bn2 = bias[gperm(w * 64 + 32 + lr)];
  float bn3 = bias[gperm(w * 64 + 48 + lr)];
  f4_t bv0 = {bn0, bn0, bn0, bn0};
  f4_t bv1 = {bn1, bn1, bn1, bn1};
  f4_t bv2 = {bn2, bn2, bn2, bn2};
  f4_t bv3 = {bn3, bn3, bn3, bn3};

  // x gather duty: thread covers (xrow, xcol)
  int xrow = tid >> 7;               // 0..3
  int xcol = tid & 127;
  bool xon = (xcol < En);
  // prologue x values: x[t0], x[t0+dt], x[t0+2dt], x[t0+3dt]
  float v0 = 0.f, v1 = 0.f, vA = 0.f, vB = 0.f;
  {
    const int* trow = text + (size_t)(b0 + xrow) * Tn;
    int k0 = trow[t0], k1 = trow[t0 + dt], k2 = trow[t0 + 2 * dt], k3 = trow[t0 + 3 * dt];
    if (xon) {
      v0 = emb[(size_t)k0 * En + xcol];
      v1 = emb[(size_t)k1 * En + xcol];
      vA = emb[(size_t)k2 * En + xcol];
      vB = emb[(size_t)k3 * En + xcol];
    }
  }

  // LDS addresses; h: read buf0 / write buf1; x: read bufB / write bufA
  int rb0 = (lr * 256 +   0 + lg * 16) ^ ((lr & 7) << 4);
  int rb1 = (lr * 256 +  64 + lg * 16) ^ ((lr & 7) << 4);
  int rb2 = (lr * 256 + 128 + lg * 16) ^ ((lr & 7) << 4);
  int rb3 = (lr * 256 + 192 + lg * 16) ^ ((lr & 7) << 4);
  int xb0 = 12288 + rb0, xb1 = 12288 + rb1, xb2 = 12288 + rb2, xb3 = 12288 + rb3;
  int wbh = (((lg * 4) * 256 + jj * 2) ^ (((lg * 4) & 7) << 4)) + 4096;
  int wbx = 8192 + (((xrow * 4) * 256 + xcol * 2) ^ (((xrow * 4) & 7) << 4));

  unsigned short* hp = hout + ((size_t)t0 * Bn + b0 + lg) * 128 + jj;
  const long long hstep = (long long)dt * Bn * 128;

  // publish x[t0] -> bufA, x[t0+dt] -> bufB
  *(unsigned short*)(lbase + wbx) = f2bf(v0);
  *(unsigned short*)(lbase + (wbx ^ 4096)) = f2bf(v1);
  bar_lgkm();                             // zeros + tokens + x publishes visible

  // prologue: P = bias + x[t0]@W (reads bufA frags)
  f4_t pA0 = bv0, pA1 = bv1, pA2 = bv2, pA3 = bv3;
  f4_t pB0, pB1, pB2, pB3;
  {
    bf8_t ax0 = *(const bf8_t*)(lbase + 8192 + rb0);
    bf8_t ax1 = *(const bf8_t*)(lbase + 8192 + rb1);
    bf8_t ax2 = *(const bf8_t*)(lbase + 8192 + rb2);
    bf8_t ax3 = *(const bf8_t*)(lbase + 8192 + rb3);
#define MFP(nt, kk) pA##nt = __builtin_amdgcn_mfma_f32_16x16x32_bf16(ax##kk, wb_##nt##_##kk, pA##nt, 0, 0, 0);
    MFP(0,0) MFP(1,0) MFP(2,0) MFP(3,0)
    MFP(0,1) MFP(1,1) MFP(2,1) MFP(3,1)
    MFP(0,2) MFP(1,2) MFP(2,2) MFP(3,2)
    MFP(0,3) MFP(1,3) MFP(2,3) MFP(3,3)
#undef MFP
  }
  float c0 = 0.f;
  int t = t0;

  // STEP(P, Q): gates from P (extended by h@U); Q = bias + x[t+1]@W for next step
#define STEPF(P, Q) { \
    bf8_t af0 = *(const bf8_t*)(lbase + rb0); \
    bf8_t af1 = *(const bf8_t*)(lbase + rb1); \
    bf8_t af2 = *(const bf8_t*)(lbase + rb2); \
    bf8_t af3 = *(const bf8_t*)(lbase + rb3); \
    /* publish x[t+2]; rotate pipeline; load x[t+3] */ \
    *(unsigned short*)(lbase + wbx) = f2bf(vA); \
    vA = vB; \
    { int tc = t + 3 * dt; tc = tc < 0 ? 0 : (tc > Tn - 1 ? Tn - 1 : tc); \
      int tokN = tl[xrow * Tn + tc]; \
      vB = xon ? emb[(size_t)tokN * En + xcol] : 0.f; } \
    /* h@U extends P in place (P already = bias + x_t@W) */ \
    P##0 = __builtin_amdgcn_mfma_f32_16x16x32_bf16(af0, ub_0_0, P##0, 0, 0, 0); \
    P##1 = __builtin_amdgcn_mfma_f32_16x16x32_bf16(af0, ub_1_0, P##1, 0, 0, 0); \
    P##2 = __builtin_amdgcn_mfma_f32_16x16x32_bf16(af0, ub_2_0, P##2, 0, 0, 0); \
    P##3 = __builtin_amdgcn_mfma_f32_16x16x32_bf16(af0, ub_3_0, P##3, 0, 0, 0); \
    P##0 = __builtin_amdgcn_mfma_f32_16x16x32_bf16(af1, ub_0_1, P##0, 0, 0, 0); \
    P##1 = __builtin_amdgcn_mfma_f32_16x16x32_bf16(af1, ub_1_1, P##1, 0, 0, 0); \
    P##2 = __builtin_amdgcn_mfma_f32_16x16x32_bf16(af1, ub_2_1, P##2, 0, 0, 0); \
    P##3 = __builtin_amdgcn_mfma_f32_16x16x32_bf16(af1, ub_3_1, P##3, 0, 0, 0); \
    P##0 = __builtin_amdgcn_mfma_f32_16x16x32_bf16(af2, ub_0_2, P##0, 0, 0, 0); \
    P##1 = __builtin_amdgcn_mfma_f32_16x16x32_bf16(af2, ub_1_2, P##1, 0, 0, 0); \
    P##2 = __builtin_amdgcn_mfma_f32_16x16x32_bf16(af2, ub_2_2, P##2, 0, 0, 0); \
    P##3 = __builtin_amdgcn_mfma_f32_16x16x32_bf16(af2, ub_3_2, P##3, 0, 0, 0); \
    P##0 = __builtin_amdgcn_mfma_f32_16x16x32_bf16(af3, ub_0_3, P##0, 0, 0, 0); \
    P##1 = __builtin_amdgcn_mfma_f32_16x16x32_bf16(af3, ub_1_3, P##1, 0, 0, 0); \
    P##2 = __builtin_amdgcn_mfma_f32_16x16x32_bf16(af3, ub_2_3, P##2, 0, 0, 0); \
    P##3 = __builtin_amdgcn_mfma_f32_16x16x32_bf16(af3, ub_3_3, P##3, 0, 0, 0); \
    /* x[t+1]@W into Q (off critical path) */ \
    { bf8_t ax0 = *(const bf8_t*)(lbase + xb0); \
      bf8_t ax1 = *(const bf8_t*)(lbase + xb1); \
      bf8_t ax2 = *(const bf8_t*)(lbase + xb2); \
      bf8_t ax3 = *(const bf8_t*)(lbase + xb3); \
      Q##0 = bv0; Q##1 = bv1; Q##2 = bv2; Q##3 = bv3; \
      Q##0 = __builtin_amdgcn_mfma_f32_16x16x32_bf16(ax0, wb_0_0, Q##0, 0, 0, 0); \
      Q##1 = __builtin_amdgcn_mfma_f32_16x16x32_bf16(ax0, wb_1_0, Q##1, 0, 0, 0); \
      Q##2 = __builtin_amdgcn_mfma_f32_16x16x32_bf16(ax0, wb_2_0, Q##2, 0, 0, 0); \
      Q##3 = __builtin_amdgcn_mfma_f32_16x16x32_bf16(ax0, wb_3_0, Q##3, 0, 0, 0); \
      Q##0 = __builtin_amdgcn_mfma_f32_16x16x32_bf16(ax1, wb_0_1, Q##0, 0, 0, 0); \
      Q##1 = __builtin_amdgcn_mfma_f32_16x16x32_bf16(ax1, wb_1_1, Q##1, 0, 0, 0); \
      Q##2 = __builtin_amdgcn_mfma_f32_16x16x32_bf16(ax1, wb_2_1, Q##2, 0, 0, 0); \
      Q##3 = __builtin_amdgcn_mfma_f32_16x16x32_bf16(ax1, wb_3_1, Q##3, 0, 0, 0); \
      Q##0 = __builtin_amdgcn_mfma_f32_16x16x32_bf16(ax2, wb_0_2, Q##0, 0, 0, 0); \
      Q##1 = __builtin_amdgcn_mfma_f32_16x16x32_bf16(ax2, wb_1_2, Q##1, 0, 0, 0); \
      Q##2 = __builtin_amdgcn_mfma_f32_16x16x32_bf16(ax2, wb_2_2, Q##2, 0, 0, 0); \
      Q##3 = __builtin_amdgcn_mfma_f32_16x16x32_bf16(ax2, wb_3_2, Q##3, 0, 0, 0); \
      Q##0 = __builtin_amdgcn_mfma_f32_16x16x32_bf16(ax3, wb_0_3, Q##0, 0, 0, 0); \
      Q##1 = __builtin_amdgcn_mfma_f32_16x16x32_bf16(ax3, wb_1_3, Q##1, 0, 0, 0); \
      Q##2 = __builtin_amdgcn_mfma_f32_16x16x32_bf16(ax3, wb_2_3, Q##2, 0, 0, 0); \
      Q##3 = __builtin_amdgcn_mfma_f32_16x16x32_bf16(ax3, wb_3_3, Q##3, 0, 0, 0); } \
    /* gates from P */ \
    float ig = sigm(P##0[0]); \
    float fg = sigm(P##1[0]); \
    float gg = fmaxf(P##2[0], 0.f); \
    c0 = fmaf(fg, c0, ig * gg); \
    unsigned short hs2 = f2bf(sigm(P##3[0]) * fmaxf(c0, 0.f)); \
    *(unsigned short*)(lbase + wbh) = hs2; \
    bar_lgkm(); \
    hp[0] = hs2; \
    rb0 ^= 4096; rb1 ^= 4096; rb2 ^= 4096; rb3 ^= 4096; \
    xb0 ^= 4096; xb1 ^= 4096; xb2 ^= 4096; xb3 ^= 4096; \
    wbh ^= 4096; wbx ^= 4096; \
    hp += hstep; \
    t += dt; }

  for (int tt = 0; tt < Tn; tt += 2) {
    STEPF(pA, pB)
    STEPF(pB, pA)
  }
#undef STEPF
}

// ---------- logits = softmax([hf|hb] @ Wd + bd); h rows are (t*Bn+b) ----------
__global__ __launch_bounds__(128) void k_logits(const unsigned short* __restrict__ hf,
                                                const unsigned short* __restrict__ hb,
                                                const float* __restrict__ Wd,
                                                const float* __restrict__ bd,
                                                float* __restrict__ out) {
  __shared__ unsigned short hs[128 * 256];   // 64KB, XOR-swizzled rows of 512B
  int tid = threadIdx.x;
  size_t row0 = (size_t)blockIdx.x * 128;
  #pragma unroll
  for (int it = 0; it < 16; it++) {
    int idx = it * 128 + tid;
    int r = idx >> 4, c = idx & 15;
    bf8_t vf = *(const bf8_t*)(hf + (row0 + r) * 128 + c * 8);
    bf8_t vb = *(const bf8_t*)(hb + (row0 + r) * 128 + c * 8);
    int byte = (r * 512 + c * 16) ^ ((r & 7) << 4);
    *(bf8_t*)((char*)hs + byte) = vf;
    int byte2 = (r * 512 + 256 + c * 16) ^ ((r & 7) << 4);
    *(bf8_t*)((char*)hs + byte2) = vb;
  }
  __syncthreads();
  float acc[Kn];
  #pragma unroll
  for (int jj = 0; jj < Kn; jj++) acc[jj] = bd[jj];
  int r = tid;
  #pragma unroll 4
  for (int c = 0; c < 32; c++) {
    int byte = (r * 512 + c * 16) ^ ((r & 7) << 4);
    bf8_t v = *(const bf8_t*)((const char*)hs + byte);
    #pragma unroll
    for (int e = 0; e < 8; e++) {
      float h = (float)v[e];
      int k = c * 8 + e;
      #pragma unroll
      for (int jj = 0; jj < Kn; jj++)
        acc[jj] = fmaf(h, Wd[k * Kn + jj], acc[jj]);   // uniform -> scalar loads
    }
  }
  float m = acc[0];
  #pragma unroll
  for (int jj = 1; jj < Kn; jj++) m = fmaxf(m, acc[jj]);
  float s = 0.f;
  #pragma unroll
  for (int jj = 0; jj < Kn; jj++) { acc[jj] = __expf(acc[jj] - m); s += acc[jj]; }
  float inv = 1.f / s;
  int rg = (int)row0 + tid;          // h row index = t*Bn + b
  int b = rg & 255, t = rg >> 8;
  float* op = out + ((size_t)b * Tn + t) * Kn;
  #pragma unroll
  for (int jj = 0; jj < Kn; jj++) op[jj] = acc[jj] * inv;
}

// ---------- CRF log-likelihood (R21): a0-shift + product-tree ----------
// Old per-step chain: 4 serial shfl_xor max-reduce + 13-deep fma chain
// (~500-650 cyc/step, shfl = LDS crossbar ~30cyc). Alpha spread is bounded
// (|a_j - a_0| <= ~3: logits in [0,1], trans in [0,1]), so shift by LANE 0's
// alpha (1 shfl) instead of the max; 13 broadcasts issue independently and
// the products reduce in a 4-deep tree. Exact max kept for final logsumexp.
__global__ __launch_bounds__(64) void k_crf(const float* __restrict__ logits,
                                            const int* __restrict__ labels,
                                            const int* __restrict__ lens_i,
                                            const float* __restrict__ trans,
                                            float* __restrict__ out_ll) {
  int b = blockIdx.x, lane = threadIdx.x;
  int len = lens_i[b];
  const float* lg = logits + (size_t)b * Tn * Kn;
  const int* lab = labels + (size_t)b * Tn;
  float sc = 0.f;
  for (int t = lane; t < Tn; t += 64) {
    if (t < len) {
      sc += lg[t * Kn + lab[t]];
      if (t >= 1) sc += trans[lab[t - 1] * Kn + lab[t]];
    }
  }
  for (int off = 32; off; off >>= 1) sc += __shfl_down(sc, off);
  bool act = lane < Kn;
  int jl = act ? lane : 0;
  float etr[Kn];
  #pragma unroll
  for (int i = 0; i < Kn; i++) etr[i] = __expf(trans[i * Kn + jl]);
  float a = act ? lg[jl] : -INFINITY;
  float lgv = (len > 1) ? lg[Kn + jl] : 0.f;
  for (int t = 1; t < len; t++) {
    float lgn = (t + 1 < len) ? lg[(t + 1) * Kn + jl] : 0.f;   // prefetch
    float a0 = __shfl(a, 0, 16);
    float ea = __expf(a - a0);          // bounded: |a - a0| <= ~3
    float p0  = __shfl(ea, 0, 16) * etr[0];
    float p1  = __shfl(ea, 1, 16) * etr[1];
    float p2  = __shfl(ea, 2, 16) * etr[2];
    float p3  = __shfl(ea, 3, 16) * etr[3];
    float p4  = __shfl(ea, 4, 16) * etr[4];
    float p5  = __shfl(ea, 5, 16) * etr[5];
    float p6  = __shfl(ea, 6, 16) * etr[6];
    float p7  = __shfl(ea, 7, 16) * etr[7];
    float p8  = __shfl(ea, 8, 16) * etr[8];
    float p9  = __shfl(ea, 9, 16) * etr[9];
    float p10 = __shfl(ea, 10, 16) * etr[10];
    float p11 = __shfl(ea, 11, 16) * etr[11];
    float p12 = __shfl(ea, 12, 16) * etr[12];
    float s01 = p0 + p1, s23 = p2 + p3, s45 = p4 + p5, s67 = p6 + p7;
    float s89 = p8 + p9, sab = p10 + p11;
    float s0123 = s01 + s23, s4567 = s45 + s67, s89ab = s89 + sab;
    float s = (s0123 + s4567) + (s89ab + p12);
    float anew = a0 + __logf(s) + lgv;
    if (act) a = anew;
    lgv = lgn;
  }
  float m2 = a;
  for (int off = 8; off; off >>= 1) m2 = fmaxf(m2, __shfl_xor(m2, off, 16));
  float ea2 = act ? __expf(a - m2) : 0.f;
  float ssum = ea2;
  for (int off = 8; off; off >>= 1) ssum += __shfl_xor(ssum, off, 16);
  float logZ = m2 + __logf(ssum);
  if (lane == 0) out_ll[b] = sc - logZ;
}

extern "C" void kernel_launch(void* const* d_in, const int* in_sizes, int n_in,
                              void* d_out, int out_size, void* d_ws, size_t ws_size,
                              hipStream_t stream) {
  const int* text = (const int*)d_in[0];
  const int* labels = (const int*)d_in[1];
  const float* emb = (const float*)d_in[2];
  const float* Wf = (const float*)d_in[3];
  const float* Uf = (const float*)d_in[4];
  const float* bf_ = (const float*)d_in[5];
  const float* Wb = (const float*)d_in[6];
  const float* Ub = (const float*)d_in[7];
  const float* bb_ = (const float*)d_in[8];
  const float* Wd = (const float*)d_in[9];
  const float* bd = (const float*)d_in[10];
  const float* trans = (const float*)d_in[11];
  (void)in_sizes; (void)n_in; (void)out_size; (void)ws_size;

  float* out = (float*)d_out;
  float* out_logits = out;                       // [BT*K]
  float* out_lens = out + (size_t)BT * Kn;       // [B]
  float* out_ll = out_lens + Bn;                 // [B]

  char* ws = (char*)d_ws;
  size_t o = 0;
  int* lens_i = (int*)(ws + o);                o += 1024;
  unsigned short* wt = (unsigned short*)(ws + o);  o += (size_t)2 * G4 * 128 * 2;
  unsigned short* ut = (unsigned short*)(ws + o);  o += (size_t)2 * G4 * 128 * 2;
  unsigned short* hfb = (unsigned short*)(ws + o); o += (size_t)BT * Hn * 2;       // [t][b][128]
  unsigned short* hbb = (unsigned short*)(ws + o); o += (size_t)BT * Hn * 2;

  hipLaunchKernelGGL(k_prep, dim3(1088), dim3(256), 0, stream,
                     text, Wf, Wb, Uf, Ub, wt, ut, lens_i, out_lens);
  hipLaunchKernelGGL(k_scan, dim3(128), dim3(512), 0, stream,
                     text, emb, wt, ut, bf_, bb_, hfb, hbb);
  hipLaunchKernelGGL(k_logits, dim3(400), dim3(128), 0, stream, hfb, hbb, Wd, bd, out_logits);
  hipLaunchKernelGGL(k_crf, dim3(Bn), dim3(64), 0, stream, out_logits, labels, lens_i, trans, out_ll);
}